// Round 12
// baseline (1067.952 us; speedup 1.0000x reference)
//
#include <hip/hip_runtime.h>

// Problem constants
#define NB   4
#define SEQ  1024
#define DIM  512
#define NH   8
#define HD   64
#define MLPD 2048
#define NL   4
#define TOPKK 256
#define QKVD 1536   // 3*DIM
#define QT   16     // queries per attention block

typedef short bh8 __attribute__((ext_vector_type(8)));
typedef float f32x4 __attribute__((ext_vector_type(4)));

// ---------- helpers ----------
__device__ __forceinline__ float b2f(unsigned short v) {
    return __uint_as_float(((unsigned)v) << 16);
}
__device__ __forceinline__ unsigned short f2b(float f) {
    unsigned u = __float_as_uint(f);
    u += 0x7FFFu + ((u >> 16) & 1u);   // RNE
    return (unsigned short)(u >> 16);
}
__device__ __forceinline__ float ldin(const void* p, size_t i, int bf) {
    return bf ? b2f(((const unsigned short*)p)[i]) : ((const float*)p)[i];
}
__device__ __forceinline__ float wave_sum(float v) {
#pragma unroll
    for (int m = 32; m; m >>= 1) v += __shfl_xor(v, m);
    return v;
}
// monotone bf16-bits -> 16-bit radix key, and inverse
__device__ __forceinline__ unsigned f2key16(unsigned short u) {
    return (u & 0x8000u) ? (unsigned)((~u) & 0xFFFFu) : (unsigned)(u | 0x8000u);
}
__device__ __forceinline__ unsigned short key16b(unsigned k) {
    return (k & 0x8000u) ? (unsigned short)(k & 0x7FFFu)
                         : (unsigned short)((~k) & 0xFFFFu);
}
// packed 2xf32 -> 2xbf16 (HW RNE)
__device__ __forceinline__ unsigned cvtpk(float a, float b) {
    unsigned r;
    asm("v_cvt_pk_bf16_f32 %0, %1, %2" : "=v"(r) : "v"(a), "v"(b));
    return r;
}
// 8 contiguous fp32 -> packed bf16x8
__device__ __forceinline__ uint4 pack8(const float* __restrict__ p) {
    uint4 r;
    r.x = (unsigned)f2b(p[0]) | ((unsigned)f2b(p[1]) << 16);
    r.y = (unsigned)f2b(p[2]) | ((unsigned)f2b(p[3]) << 16);
    r.z = (unsigned)f2b(p[4]) | ((unsigned)f2b(p[5]) << 16);
    r.w = (unsigned)f2b(p[6]) | ((unsigned)f2b(p[7]) << 16);
    return r;
}
// async 16B/lane global->LDS: LDS dest = wave-uniform base + lane*16
__device__ __forceinline__ void async16(unsigned short* lds, const unsigned short* g) {
    __builtin_amdgcn_global_load_lds(
        (const __attribute__((address_space(1))) unsigned int*)g,
        (__attribute__((address_space(3))) unsigned int*)lds, 16, 0, 0);
}

// ---------- kernels ----------

__global__ void detect_kernel(const unsigned short* __restrict__ ln1w,
                              int* __restrict__ flag) {
    if (threadIdx.x == 0 && blockIdx.x == 0)
        *flag = (ln1w[0] == 0x3F80u) ? 1 : 0;
}

// convert weight array (input dtype) -> bf16 scratch
__global__ __launch_bounds__(256) void wcvt_kernel(
    const void* __restrict__ W, unsigned short* __restrict__ out,
    int n, const int* __restrict__ dflag) {
    int bf = *dflag;
    int idx = blockIdx.x * 256 + threadIdx.x;
    if (idx < n) out[idx] = f2b(ldin(W, idx, bf));
}

__global__ __launch_bounds__(256) void addpos_kernel(
    const void* __restrict__ x, const void* __restrict__ pos,
    float* __restrict__ h, const int* __restrict__ dflag) {
    int bf = *dflag;
    int idx = blockIdx.x * 256 + threadIdx.x;
    int sd = idx & (SEQ * DIM - 1);
    h[idx] = ldin(x, idx, bf) + ldin(pos, sd, bf);
}

// layernorm over last dim (512): fp32 in, bf16 out. w/b at element offset wo.
// One WAVE per row (4 rows/block), pure shfl reduce.
// Optional fused partial add: x = io + P (fp32), write back io, LN(x).
__global__ __launch_bounds__(256) void ln_kernel(
    float* __restrict__ io, const float* __restrict__ P,
    const void* __restrict__ w, const void* __restrict__ bb, size_t wo,
    unsigned short* __restrict__ out, const int* __restrict__ dflag) {
    int bf = *dflag;
    int tid = threadIdx.x;
    int lane = tid & 63, wid = tid >> 6;
    int row = blockIdx.x * 4 + wid;
    float* p = io + (size_t)row * DIM + lane * 8;
    float4 x0 = *(const float4*)(p);
    float4 x1 = *(const float4*)(p + 4);
    float d[8] = {x0.x, x0.y, x0.z, x0.w, x1.x, x1.y, x1.z, x1.w};
    if (P) {
        const float* pp = P + (size_t)row * DIM + lane * 8;
        float4 q0 = *(const float4*)(pp);
        float4 q1 = *(const float4*)(pp + 4);
        d[0] += q0.x; d[1] += q0.y; d[2] += q0.z; d[3] += q0.w;
        d[4] += q1.x; d[5] += q1.y; d[6] += q1.z; d[7] += q1.w;
        *(float4*)(p)     = (float4){d[0], d[1], d[2], d[3]};
        *(float4*)(p + 4) = (float4){d[4], d[5], d[6], d[7]};
    }
    float s = (d[0] + d[1]) + (d[2] + d[3]) + (d[4] + d[5]) + (d[6] + d[7]);
    s = wave_sum(s);
    float mean = s * (1.0f / DIM);
    float q = 0.f;
#pragma unroll
    for (int j = 0; j < 8; ++j) {
        d[j] -= mean;
        q += d[j] * d[j];
    }
    q = wave_sum(q);
    float rs = rsqrtf(q * (1.0f / DIM) + 1e-6f);
    size_t eo = wo + lane * 8;
    unsigned short* o = out + (size_t)row * DIM + lane * 8;
    unsigned pw[4];
#pragma unroll
    for (int j = 0; j < 4; ++j) {
        float v0 = d[2 * j]     * rs * ldin(w, eo + 2 * j, bf)     + ldin(bb, eo + 2 * j, bf);
        float v1 = d[2 * j + 1] * rs * ldin(w, eo + 2 * j + 1, bf) + ldin(bb, eo + 2 * j + 1, bf);
        pw[j] = (unsigned)f2b(v0) | ((unsigned)f2b(v1) << 16);
    }
    *(uint4*)o = (uint4){pw[0], pw[1], pw[2], pw[3]};
}

// final layernorm: fp32 in (+ optional fp32 partial), output in detected dtype
__global__ __launch_bounds__(256) void lnf_kernel(
    const float* __restrict__ in, const float* __restrict__ P,
    const void* __restrict__ w, const void* __restrict__ bb,
    void* __restrict__ out, const int* __restrict__ dflag) {
    int bf = *dflag;
    __shared__ float red[4];
    int row = blockIdx.x, tid = threadIdx.x;
    int lane = tid & 63, wid = tid >> 6;
    const float* p = in + (size_t)row * DIM;
    float x0 = p[tid], x1 = p[tid + 256];
    if (P) {
        const float* pp = P + (size_t)row * DIM;
        x0 += pp[tid];
        x1 += pp[tid + 256];
    }
    float s = wave_sum(x0 + x1);
    if (!lane) red[wid] = s;
    __syncthreads();
    float mean = (red[0] + red[1] + red[2] + red[3]) * (1.0f / DIM);
    float d0 = x0 - mean, d1 = x1 - mean;
    float q = wave_sum(d0 * d0 + d1 * d1);
    __syncthreads();
    if (!lane) red[wid] = q;
    __syncthreads();
    float var = (red[0] + red[1] + red[2] + red[3]) * (1.0f / DIM);
    float rs = rsqrtf(var + 1e-6f);
    float v0 = d0 * rs * ldin(w, tid, bf) + ldin(bb, tid, bf);
    float v1 = d1 * rs * ldin(w, tid + 256, bf) + ldin(bb, tid + 256, bf);
    size_t o = (size_t)row * DIM;
    if (bf) {
        ((unsigned short*)out)[o + tid]       = f2b(v0);
        ((unsigned short*)out)[o + tid + 256] = f2b(v1);
    } else {
        ((float*)out)[o + tid]       = v0;
        ((float*)out)[o + tid + 256] = v1;
    }
}

// ---- fallback GEMMs (inline fp32->bf16 pack) ----
__global__ __launch_bounds__(256) void gemm_mfma_kernel(
    const unsigned short* __restrict__ A, const void* __restrict__ W, size_t wo,
    const void* __restrict__ bias, size_t bo, void* __restrict__ C,
    int M, int N, int K, int flags, const int* __restrict__ dflag) {
    int bf = *dflag;
    __shared__ unsigned short As[128 * 32];
    __shared__ unsigned short Bs[128 * 32];
    int tid = threadIdx.x;
    int w = tid >> 6, l = tid & 63;
    int n0 = blockIdx.x * 128, m0 = blockIdx.y * 128;
    int wm = (w >> 1) * 64, wn = (w & 1) * 64;
    int lq = l & 15, lk = l >> 4;

    int srow = w * 32 + (l >> 2);
    int cb = (l & 3) * 8;
    const unsigned short* aG = A + (size_t)(m0 + srow) * K + cb;
    size_t wb = wo + (size_t)(n0 + srow) * K + cb;
    unsigned short* sA0 = &As[w * 1024 + l * 8];
    unsigned short* sA1 = &As[w * 1024 + 512 + l * 8];
    unsigned short* sB0 = &Bs[w * 1024 + l * 8];
    unsigned short* sB1 = &Bs[w * 1024 + 512 + l * 8];

    f32x4 acc[4][4];
#pragma unroll
    for (int i = 0; i < 4; ++i)
#pragma unroll
        for (int j = 0; j < 4; ++j)
            acc[i][j] = (f32x4){0.f, 0.f, 0.f, 0.f};

    for (int k0 = 0; k0 < K; k0 += 32) {
        uint4 a0 = *(const uint4*)(aG + k0);
        uint4 a1 = *(const uint4*)(aG + 16 * K + k0);
        uint4 b0, b1;
        if (bf) {
            b0 = *(const uint4*)((const unsigned short*)W + wb + k0);
            b1 = *(const uint4*)((const unsigned short*)W + wb + 16 * K + k0);
        } else {
            b0 = pack8((const float*)W + wb + k0);
            b1 = pack8((const float*)W + wb + 16 * K + k0);
        }
        __syncthreads();
        *(uint4*)sA0 = a0;
        *(uint4*)sA1 = a1;
        *(uint4*)sB0 = b0;
        *(uint4*)sB1 = b1;
        __syncthreads();
        bh8 af[4], bw[4];
#pragma unroll
        for (int i = 0; i < 4; ++i) {
            af[i] = *(const bh8*)&As[(wm + i * 16 + lq) * 32 + lk * 8];
            bw[i] = *(const bh8*)&Bs[(wn + i * 16 + lq) * 32 + lk * 8];
        }
#pragma unroll
        for (int i = 0; i < 4; ++i)
#pragma unroll
            for (int j = 0; j < 4; ++j)
                acc[i][j] = __builtin_amdgcn_mfma_f32_16x16x32_bf16(
                    af[i], bw[j], acc[i][j], 0, 0, 0);
    }

    int lr4 = lk * 4;
#pragma unroll
    for (int i = 0; i < 4; ++i) {
#pragma unroll
        for (int j = 0; j < 4; ++j) {
            int n = n0 + wn + j * 16 + lq;
            float bv = (flags & 4) ? ldin(bias, bo + n, bf) : 0.0f;
#pragma unroll
            for (int r = 0; r < 4; ++r) {
                int m = m0 + wm + i * 16 + lr4 + r;
                float v = acc[i][j][r] + bv;
                if (flags & 2) v = 0.5f * v * (1.0f + erff(v * 0.70710678118654752f));
                size_t o = (size_t)m * N + n;
                if (flags & 1) ((float*)C)[o] += v;
                else           ((unsigned short*)C)[o] = f2b(v);
            }
        }
    }
}

__global__ __launch_bounds__(256) void gemm_mfma_n64_kernel(
    const unsigned short* __restrict__ A, const void* __restrict__ W, size_t wo,
    const void* __restrict__ bias, size_t bo, void* __restrict__ C,
    int M, int N, int K, int flags, const int* __restrict__ dflag) {
    int bf = *dflag;
    __shared__ unsigned short As[128 * 32];
    __shared__ unsigned short Bs[64 * 32];
    int tid = threadIdx.x;
    int w = tid >> 6, l = tid & 63;
    int n0 = blockIdx.x * 64, m0 = blockIdx.y * 128;
    int wm = (w >> 1) * 64, wn = (w & 1) * 32;
    int lq = l & 15, lk = l >> 4;

    int srowA = w * 32 + (l >> 2);
    int cb = (l & 3) * 8;
    const unsigned short* aG = A + (size_t)(m0 + srowA) * K + cb;
    int srowB = w * 16 + (l >> 2);
    size_t wb = wo + (size_t)(n0 + srowB) * K + cb;
    unsigned short* sA0 = &As[w * 1024 + l * 8];
    unsigned short* sA1 = &As[w * 1024 + 512 + l * 8];
    unsigned short* sB0 = &Bs[w * 512 + l * 8];

    f32x4 acc[4][2];
#pragma unroll
    for (int i = 0; i < 4; ++i) {
        acc[i][0] = (f32x4){0.f, 0.f, 0.f, 0.f};
        acc[i][1] = (f32x4){0.f, 0.f, 0.f, 0.f};
    }

    for (int k0 = 0; k0 < K; k0 += 32) {
        uint4 a0 = *(const uint4*)(aG + k0);
        uint4 a1 = *(const uint4*)(aG + 16 * K + k0);
        uint4 b0;
        if (bf) b0 = *(const uint4*)((const unsigned short*)W + wb + k0);
        else    b0 = pack8((const float*)W + wb + k0);
        __syncthreads();
        *(uint4*)sA0 = a0;
        *(uint4*)sA1 = a1;
        *(uint4*)sB0 = b0;
        __syncthreads();
        bh8 af[4], bw[2];
#pragma unroll
        for (int i = 0; i < 4; ++i)
            af[i] = *(const bh8*)&As[(wm + i * 16 + lq) * 32 + lk * 8];
        bw[0] = *(const bh8*)&Bs[(wn + lq) * 32 + lk * 8];
        bw[1] = *(const bh8*)&Bs[(wn + 16 + lq) * 32 + lk * 8];
#pragma unroll
        for (int i = 0; i < 4; ++i) {
            acc[i][0] = __builtin_amdgcn_mfma_f32_16x16x32_bf16(af[i], bw[0], acc[i][0], 0, 0, 0);
            acc[i][1] = __builtin_amdgcn_mfma_f32_16x16x32_bf16(af[i], bw[1], acc[i][1], 0, 0, 0);
        }
    }

    int lr4 = lk * 4;
#pragma unroll
    for (int i = 0; i < 4; ++i) {
#pragma unroll
        for (int j = 0; j < 2; ++j) {
            int n = n0 + wn + j * 16 + lq;
            float bv = (flags & 4) ? ldin(bias, bo + n, bf) : 0.0f;
#pragma unroll
            for (int r = 0; r < 4; ++r) {
                int m = m0 + wm + i * 16 + lr4 + r;
                float v = acc[i][j][r] + bv;
                if (flags & 2) v = 0.5f * v * (1.0f + erff(v * 0.70710678118654752f));
                size_t o = (size_t)m * N + n;
                if (flags & 1) ((float*)C)[o] += v;
                else           ((unsigned short*)C)[o] = f2b(v);
            }
        }
    }
}

// ---- main-path GEMM: 128Mx64N, bf16 weights, global_load_lds staging,
// double-buffered 2-phase pipeline.
// split-K (flags&8): NO atomics — kz==0 does owner "C += v", kz==1 plain-
// stores partial to Cp; the following LN kernel fuses "h += Cp".
// flags: 1 = plain fp32 +=, 2 = GELU->bf16, 0 = bf16 store, 4 = bias, 8 = split
__global__ __launch_bounds__(256) void gemm_n64_dlds_kernel(
    const unsigned short* __restrict__ A, const unsigned short* __restrict__ W, size_t wo,
    const void* __restrict__ bias, size_t bo, void* __restrict__ C,
    float* __restrict__ Cp,
    int M, int N, int K, int flags, const int* __restrict__ dflag) {
    __shared__ unsigned short As[2][128 * 32];
    __shared__ unsigned short Bs[2][64 * 32];
    int tid = threadIdx.x;
    int w = tid >> 6, l = tid & 63;
    int n0 = blockIdx.x * 64, m0 = blockIdx.y * 128;
    int kz = blockIdx.z;
    int Ks = K / (int)gridDim.z;
    int kbeg = kz * Ks;
    int nt = Ks / 32;
    int wm = (w >> 1) * 64, wn = (w & 1) * 32;
    int lq = l & 15, lk = l >> 4;

    int srowA = w * 32 + (l >> 2);
    int srowB = w * 16 + (l >> 2);
    int cb = (l & 3) * 8;
    const unsigned short* aG = A + (size_t)(m0 + srowA) * K + cb + kbeg;
    const unsigned short* wG = W + wo + (size_t)(n0 + srowB) * K + cb + kbeg;

    f32x4 acc[4][2];
#pragma unroll
    for (int i = 0; i < 4; ++i) {
        acc[i][0] = (f32x4){0.f, 0.f, 0.f, 0.f};
        acc[i][1] = (f32x4){0.f, 0.f, 0.f, 0.f};
    }

    // prologue: stage tile 0 into buffer 0
    async16(&As[0][w * 1024], aG);
    async16(&As[0][w * 1024 + 512], aG + 16 * K);
    async16(&Bs[0][w * 512], wG);

    int cur = 0;
    for (int t = 0; t < nt; ++t) {
        asm volatile("s_waitcnt vmcnt(0)" ::: "memory");
        __builtin_amdgcn_s_barrier();
        if (t + 1 < nt) {
            int k1 = (t + 1) * 32;
            async16(&As[cur ^ 1][w * 1024], aG + k1);
            async16(&As[cur ^ 1][w * 1024 + 512], aG + 16 * K + k1);
            async16(&Bs[cur ^ 1][w * 512], wG + k1);
        }
        bh8 af[4], bw[2];
#pragma unroll
        for (int i = 0; i < 4; ++i)
            af[i] = *(const bh8*)&As[cur][(wm + i * 16 + lq) * 32 + lk * 8];
        bw[0] = *(const bh8*)&Bs[cur][(wn + lq) * 32 + lk * 8];
        bw[1] = *(const bh8*)&Bs[cur][(wn + 16 + lq) * 32 + lk * 8];
#pragma unroll
        for (int i = 0; i < 4; ++i) {
            acc[i][0] = __builtin_amdgcn_mfma_f32_16x16x32_bf16(af[i], bw[0], acc[i][0], 0, 0, 0);
            acc[i][1] = __builtin_amdgcn_mfma_f32_16x16x32_bf16(af[i], bw[1], acc[i][1], 0, 0, 0);
        }
        cur ^= 1;
    }

    int bf = (flags & 4) ? *dflag : 0;
    int lr4 = lk * 4;
#pragma unroll
    for (int i = 0; i < 4; ++i) {
#pragma unroll
        for (int j = 0; j < 2; ++j) {
            int n = n0 + wn + j * 16 + lq;
            float bv = ((flags & 4) && kz == 0) ? ldin(bias, bo + n, bf) : 0.0f;
#pragma unroll
            for (int r = 0; r < 4; ++r) {
                int m = m0 + wm + i * 16 + lr4 + r;
                float v = acc[i][j][r] + bv;
                if (flags & 2) v = 0.5f * v * (1.0f + erff(v * 0.70710678118654752f));
                size_t o = (size_t)m * N + n;
                if (flags & 8) {
                    if (kz == 0) ((float*)C)[o] += v;   // unique owner, no atomics
                    else         Cp[o] = v;             // partial slice, plain store
                } else if (flags & 1) ((float*)C)[o] += v;
                else                  ((unsigned short*)C)[o] = f2b(v);
            }
        }
    }
}

// ---- v12: 128Mx128N double-buffered GEMM (qkv / mlp1).
// 16 MFMA per 8 b128 LDS reads per K-step = 2x FLOP per LDS byte vs n64
// (the n64 inner loop is LDS-BW-bound: ~56KB LDS traffic/block-iter vs
// 160cy of MFMA). LDS 2x16KB, ~2 blocks/CU, load latency hides under the
// 16-MFMA phase. Same k-ascending accumulation order -> bitwise-identical.
__global__ __launch_bounds__(256) void gemm_n128_dlds_kernel(
    const unsigned short* __restrict__ A, const unsigned short* __restrict__ W, size_t wo,
    const void* __restrict__ bias, size_t bo, void* __restrict__ C,
    int M, int N, int K, int flags, const int* __restrict__ dflag) {
    __shared__ unsigned short As[2][128 * 32];
    __shared__ unsigned short Bs[2][128 * 32];
    int tid = threadIdx.x;
    int w = tid >> 6, l = tid & 63;
    int n0 = blockIdx.x * 128, m0 = blockIdx.y * 128;
    int nt = K / 32;
    int wm = (w >> 1) * 64, wn = (w & 1) * 64;
    int lq = l & 15, lk = l >> 4;

    int srow = w * 32 + (l >> 2);
    int cb = (l & 3) * 8;
    const unsigned short* aG = A + (size_t)(m0 + srow) * K + cb;
    const unsigned short* wG = W + wo + (size_t)(n0 + srow) * K + cb;

    f32x4 acc[4][4];
#pragma unroll
    for (int i = 0; i < 4; ++i)
#pragma unroll
        for (int j = 0; j < 4; ++j)
            acc[i][j] = (f32x4){0.f, 0.f, 0.f, 0.f};

    // prologue: stage tile 0 into buffer 0
    async16(&As[0][w * 1024], aG);
    async16(&As[0][w * 1024 + 512], aG + 16 * K);
    async16(&Bs[0][w * 1024], wG);
    async16(&Bs[0][w * 1024 + 512], wG + 16 * K);

    int cur = 0;
    for (int t = 0; t < nt; ++t) {
        asm volatile("s_waitcnt vmcnt(0)" ::: "memory");
        __builtin_amdgcn_s_barrier();
        if (t + 1 < nt) {
            int k1 = (t + 1) * 32;
            async16(&As[cur ^ 1][w * 1024], aG + k1);
            async16(&As[cur ^ 1][w * 1024 + 512], aG + 16 * K + k1);
            async16(&Bs[cur ^ 1][w * 1024], wG + k1);
            async16(&Bs[cur ^ 1][w * 1024 + 512], wG + 16 * K + k1);
        }
        bh8 af[4], bw[4];
#pragma unroll
        for (int i = 0; i < 4; ++i) {
            af[i] = *(const bh8*)&As[cur][(wm + i * 16 + lq) * 32 + lk * 8];
            bw[i] = *(const bh8*)&Bs[cur][(wn + i * 16 + lq) * 32 + lk * 8];
        }
#pragma unroll
        for (int i = 0; i < 4; ++i)
#pragma unroll
            for (int j = 0; j < 4; ++j)
                acc[i][j] = __builtin_amdgcn_mfma_f32_16x16x32_bf16(
                    af[i], bw[j], acc[i][j], 0, 0, 0);
        cur ^= 1;
    }

    int bf = (flags & 4) ? *dflag : 0;
    int lr4 = lk * 4;
#pragma unroll
    for (int i = 0; i < 4; ++i) {
#pragma unroll
        for (int j = 0; j < 4; ++j) {
            int n = n0 + wn + j * 16 + lq;
            float bv = (flags & 4) ? ldin(bias, bo + n, bf) : 0.0f;
#pragma unroll
            for (int r = 0; r < 4; ++r) {
                int m = m0 + wm + i * 16 + lr4 + r;
                float v = acc[i][j][r] + bv;
                if (flags & 2) v = 0.5f * v * (1.0f + erff(v * 0.70710678118654752f));
                size_t o = (size_t)m * N + n;
                if (flags & 1) ((float*)C)[o] += v;
                else           ((unsigned short*)C)[o] = f2b(v);
            }
        }
    }
}

// fused depthwise conv (k=3 along s) + q/k normalize + scatter.
__global__ __launch_bounds__(256) void dwqkv_kernel(
    const unsigned short* __restrict__ in, const void* __restrict__ w, size_t wo,
    const void* __restrict__ temp, size_t to,
    unsigned short* __restrict__ qn, unsigned short* __restrict__ Kc,
    unsigned short* __restrict__ Vt, const int* __restrict__ dflag) {
    int bf = *dflag;
    int tid = threadIdx.x;
    int g = tid >> 6, c = tid & 63;
    int gid = blockIdx.x * 4 + g;          // (b*S+s)*H + h
    int h = gid & 7;
    int bs = gid >> 3;
    int s = bs & (SEQ - 1), b = bs >> 10;
    int bh = b * NH + h;
    const unsigned short* row = in + (size_t)bs * QKVD;
    float vals[3];
#pragma unroll
    for (int t = 0; t < 3; ++t) {
        int o = t * 512 + h * HD + c;
        float w0 = ldin(w, wo + o * 3 + 0, bf);
        float w1 = ldin(w, wo + o * 3 + 1, bf);
        float w2 = ldin(w, wo + o * 3 + 2, bf);
        float a = w1 * b2f(row[o]);
        if (s > 0)       a += w0 * b2f(row[o - QKVD]);
        if (s < SEQ - 1) a += w2 * b2f(row[o + QKVD]);
        vals[t] = a;
    }
    float qs = wave_sum(vals[0] * vals[0]);
    float ks = wave_sum(vals[1] * vals[1]);
    float t_ = ldin(temp, to + h, bf);
    qn[(size_t)bs * DIM + h * HD + c] = f2b(vals[0] / fmaxf(sqrtf(qs), 1e-12f) * t_);
    Kc[((size_t)bh * SEQ + s) * HD + c] = f2b(vals[1] / fmaxf(sqrtf(ks), 1e-12f));
    Vt[(((size_t)bh * 32 + (s >> 5)) * HD + c) * 32 + (s & 31)] = f2b(vals[2]);
}

// Q-tiled MFMA attention (v5 structure + v9 select ILP).
__global__ __launch_bounds__(256) void attn_kernel(
    const unsigned short* __restrict__ q, const unsigned short* __restrict__ Kc,
    const unsigned short* __restrict__ Vt, unsigned short* __restrict__ outp) {
    __shared__ __align__(16) unsigned short sc16[QT * 1024];

    int tid = threadIdx.x;
    int w = tid >> 6, l = tid & 63;
    int lq = l & 15, lk = l >> 4;
    int bid = blockIdx.x;
    int qt = (bid >> 3) & 63;
    int bh = ((bid >> 9) << 3) | (bid & 7);   // XCD-locality remap (bijective)
    int h = bh & 7;
    int b = bh >> 3;

    const unsigned short* qp = q + (size_t)(b * SEQ + qt * QT + lq) * DIM + h * HD + lk * 8;
    bh8 aq0 = *(const bh8*)(qp);
    bh8 aq1 = *(const bh8*)(qp + 32);

    int swz = ((lq ^ (lq >> 2)) & 7) << 1;   // per-q-row chunk4 XOR (bits 1-3)

    const unsigned short* Kbh = Kc + (size_t)bh * SEQ * HD;
    unsigned short* srowq = sc16 + lq * 1024;
    for (int kb = 0; kb < 16; kb += 2) {
        int key0 = (w * 16 + kb) * 16;
        const unsigned short* kp0 = Kbh + (size_t)(key0 + lq) * HD + lk * 8;
        const unsigned short* kp1 = kp0 + 16 * HD;
        bh8 b0 = *(const bh8*)(kp0);
        bh8 b1 = *(const bh8*)(kp0 + 32);
        bh8 b2 = *(const bh8*)(kp1);
        bh8 b3 = *(const bh8*)(kp1 + 32);
        f32x4 a0 = {0.f, 0.f, 0.f, 0.f};
        f32x4 a1 = {0.f, 0.f, 0.f, 0.f};
        a0 = __builtin_amdgcn_mfma_f32_16x16x32_bf16(b0, aq0, a0, 0, 0, 0);
        a0 = __builtin_amdgcn_mfma_f32_16x16x32_bf16(b1, aq1, a0, 0, 0, 0);
        a1 = __builtin_amdgcn_mfma_f32_16x16x32_bf16(b2, aq0, a1, 0, 0, 0);
        a1 = __builtin_amdgcn_mfma_f32_16x16x32_bf16(b3, aq1, a1, 0, 0, 0);
        int c0 = (key0 >> 2) + lk;
        uint2 w0 = {cvtpk(a0[0], a0[1]), cvtpk(a0[2], a0[3])};
        uint2 w1 = {cvtpk(a1[0], a1[1]), cvtpk(a1[2], a1[3])};
        *(uint2*)&srowq[(c0 ^ swz) << 2]       = w0;
        *(uint2*)&srowq[((c0 + 4) ^ swz) << 2] = w1;
    }
    __syncthreads();

    for (int rr = 0; rr < 4; rr += 2) {
        int rowA = w * 4 + rr;
        unsigned short* sAr = sc16 + rowA * 1024;
        unsigned short* sBr = sc16 + (rowA + 1) * 1024;
        uint4 ra0 = *(const uint4*)&sAr[l * 8];
        uint4 ra1 = *(const uint4*)&sAr[512 + l * 8];
        uint4 rb0 = *(const uint4*)&sBr[l * 8];
        uint4 rb1 = *(const uint4*)&sBr[512 + l * 8];
        unsigned wa[8] = {ra0.x, ra0.y, ra0.z, ra0.w, ra1.x, ra1.y, ra1.z, ra1.w};
        unsigned wb[8] = {rb0.x, rb0.y, rb0.z, rb0.w, rb1.x, rb1.y, rb1.z, rb1.w};
        float va[16], vb[16];
#pragma unroll
        for (int j = 0; j < 8; ++j) {
            va[2 * j]     = __uint_as_float(wa[j] << 16);
            va[2 * j + 1] = __uint_as_float(wa[j] & 0xFFFF0000u);
            vb[2 * j]     = __uint_as_float(wb[j] << 16);
            vb[2 * j + 1] = __uint_as_float(wb[j] & 0xFFFF0000u);
        }
        float ma = va[0], mb = vb[0];
#pragma unroll
        for (int j = 1; j < 16; ++j) {
            ma = fmaxf(ma, va[j]);
            mb = fmaxf(mb, vb[j]);
        }
#pragma unroll
        for (int off = 1; off < 64; off <<= 1) {
            ma = fmaxf(ma, __shfl_xor(ma, off));
            mb = fmaxf(mb, __shfl_xor(mb, off));
        }
        ma = fminf(fmaxf(ma, -10000.f), 10000.f);
        mb = fminf(fmaxf(mb, -10000.f), 10000.f);
        unsigned Ta = 0, Tb = 0;
        for (int bit = 15; bit >= 0; --bit) {
            unsigned ca = Ta | (1u << bit), cb = Tb | (1u << bit);
            float tfa = b2f(key16b(ca)), tfb = b2f(key16b(cb));
            unsigned cna = 0, cnb = 0;
#pragma unroll
            for (int j = 0; j < 16; ++j) {
                cna += (unsigned)__popcll(__ballot(va[j] >= tfa));
                cnb += (unsigned)__popcll(__ballot(vb[j] >= tfb));
            }
            if (cna >= TOPKK) Ta = ca;
            if (cnb >= TOPKK) Tb = cb;
        }
        float ka = b2f(key16b(Ta)), kb = b2f(key16b(Tb));
        float sa = 0.f, sb = 0.f;
#pragma unroll
        for (int j = 0; j < 16; ++j) {
            float aa = fminf(fmaxf(va[j], -10000.f), 10000.f);
            float ab = fminf(fmaxf(vb[j], -10000.f), 10000.f);
            float ea = (va[j] >= ka) ? __expf(aa - ma) : 0.0f;
            float eb = (vb[j] >= kb) ? __expf(ab - mb) : 0.0f;
            sa += ea; sb += eb;
            va[j] = ea; vb[j] = eb;
        }
#pragma unroll
        for (int off = 1; off < 64; off <<= 1) {
            sa += __shfl_xor(sa, off);
            sb += __shfl_xor(sb, off);
        }
        float ia = 1.0f / sa, ib = 1.0f / sb;
        unsigned pa[8], pb[8];
#pragma unroll
        for (int j = 0; j < 8; ++j) {
            pa[j] = cvtpk(va[2 * j] * ia, va[2 * j + 1] * ia);
            pb[j] = cvtpk(vb[2 * j] * ib, vb[2 * j + 1] * ib);
        }
        *(uint4*)&sAr[l * 8]       = (uint4){pa[0], pa[1], pa[2], pa[3]};
        *(uint4*)&sAr[512 + l * 8] = (uint4){pa[4], pa[5], pa[6], pa[7]};
        *(uint4*)&sBr[l * 8]       = (uint4){pb[0], pb[1], pb[2], pb[3]};
        *(uint4*)&sBr[512 + l * 8] = (uint4){pb[4], pb[5], pb[6], pb[7]};
    }
    __syncthreads();

    {
        const unsigned short* Vbh = Vt + (size_t)bh * SEQ * HD;
        const unsigned short* prow = sc16 + lq * 1024;
        f32x4 oacc = {0.f, 0.f, 0.f, 0.f};
        for (int tc = 0; tc < 32; tc += 2) {
            const unsigned short* vp0 = Vbh + (size_t)tc * 2048 + (w * 16 + lq) * 32 + lk * 8;
            bh8 bv0 = *(const bh8*)(vp0);
            bh8 bv1 = *(const bh8*)(vp0 + 2048);
            bh8 ap0 = *(const bh8*)&prow[((tc * 8 + lk * 2) ^ swz) << 2];
            bh8 ap1 = *(const bh8*)&prow[(((tc + 1) * 8 + lk * 2) ^ swz) << 2];
            oacc = __builtin_amdgcn_mfma_f32_16x16x32_bf16(ap0, bv0, oacc, 0, 0, 0);
            oacc = __builtin_amdgcn_mfma_f32_16x16x32_bf16(ap1, bv1, oacc, 0, 0, 0);
        }
#pragma unroll
        for (int r = 0; r < 4; ++r) {
            int qrow = lk * 4 + r;
            outp[((size_t)(b * SEQ + qt * QT + qrow)) * DIM + h * HD + w * 16 + lq] = f2b(oacc[r]);
        }
    }
}

// ---------- host ----------
extern "C" void kernel_launch(void* const* d_in, const int* in_sizes, int n_in,
                              void* d_out, int out_size, void* d_ws, size_t ws_size,
                              hipStream_t stream) {
    (void)in_sizes; (void)n_in; (void)out_size;
    const void* x     = d_in[0];
    const void* pos   = d_in[1];
    const void* ln1w  = d_in[2];
    const void* ln1b  = d_in[3];
    const void* qkvw  = d_in[4];
    const void* dww   = d_in[5];
    const void* temp  = d_in[6];
    const void* projw = d_in[7];
    const void* ln2w  = d_in[8];
    const void* ln2b  = d_in[9];
    const void* w1    = d_in[10];
    const void* b1    = d_in[11];
    const void* w2    = d_in[12];
    const void* b2    = d_in[13];
    const void* lnfw  = d_in[14];
    const void* lnfb  = d_in[15];

    // ws layout (float units): h[0,2M) | bn@2M | C2/Mb/Pp@3M | Vt@6M |
    // Kc/Pm@7M | flag@9M | Wc@(9M+16).
    // Pp (proj partial, fp32 2M floats) = [3M,5M): C2 dead in proj->ln2 window.
    // Pm (mlp2 partial, fp32 2M floats) = [7M,9M): Kc dead in mlp2->ln1' window.
    float* wsf = (float*)d_ws;
    const size_t M1 = (size_t)1024 * 1024;
    float*          h    = wsf;
    unsigned short* bn   = (unsigned short*)(wsf + 2 * M1);
    unsigned short* C2   = (unsigned short*)(wsf + 3 * M1);
    unsigned short* Vt   = (unsigned short*)(wsf + 6 * M1);
    unsigned short* Kc   = (unsigned short*)(wsf + 7 * M1);
    unsigned short* Mb   = C2;
    float*          Pp   = wsf + 3 * M1;
    float*          Pm   = wsf + 7 * M1;
    int*            flag = (int*)(wsf + 9 * M1);
    unsigned short* Wc   = (unsigned short*)(wsf + 9 * M1 + 16);

    const int MTOK  = NB * SEQ;                       // 4096
    const int nQKVW = NL * QKVD * DIM;                // 3145728
    const int nPROJ = NL * DIM * DIM;                 // 1048576
    const int nW1   = NL * MLPD * DIM;                // 4194304
    const int nW2   = NL * DIM * MLPD;                // 4194304
    const size_t wcElems = (size_t)nQKVW + nPROJ + nW1 + nW2;   // 12582912
    const int big = ws_size >= ((9 * M1 + 16) * 4 + wcElems * 2);

    unsigned short* WcQ  = Wc;
    unsigned short* WcP  = Wc + nQKVW;
    unsigned short* WcW1 = Wc + nQKVW + nPROJ;
    unsigned short* WcW2 = Wc + nQKVW + nPROJ + (size_t)nW1;

    detect_kernel<<<1, 64, 0, stream>>>((const unsigned short*)ln1w, flag);
    addpos_kernel<<<(NB * SEQ * DIM) / 256, 256, 0, stream>>>(x, pos, h, flag);

    if (big) {
        wcvt_kernel<<<nQKVW / 256, 256, 0, stream>>>(qkvw, WcQ, nQKVW, flag);
        wcvt_kernel<<<nPROJ / 256, 256, 0, stream>>>(projw, WcP, nPROJ, flag);
        wcvt_kernel<<<nW1 / 256, 256, 0, stream>>>(w1, WcW1, nW1, flag);
        wcvt_kernel<<<nW2 / 256, 256, 0, stream>>>(w2, WcW2, nW2, flag);
    }

    for (int l = 0; l < NL; ++l) {
        // ln1: layer 0 has no pending mlp2 partial; later layers fold Pm.
        const float* P1 = (big && l > 0) ? Pm : nullptr;
        ln_kernel<<<MTOK / 4, 256, 0, stream>>>(h, P1, ln1w, ln1b, (size_t)l * DIM, bn, flag);
        if (big) {
            gemm_n128_dlds_kernel<<<dim3(QKVD / 128, MTOK / 128), 256, 0, stream>>>(
                bn, WcQ, (size_t)l * QKVD * DIM, nullptr, 0, C2,
                MTOK, QKVD, DIM, 0, flag);
        } else {
            gemm_mfma_kernel<<<dim3(QKVD / 128, MTOK / 128), 256, 0, stream>>>(
                bn, qkvw, (size_t)l * QKVD * DIM, nullptr, 0, C2,
                MTOK, QKVD, DIM, 0, flag);
        }
        dwqkv_kernel<<<(NB * SEQ * NH) / 4, 256, 0, stream>>>(
            C2, dww, (size_t)l * QKVD * 3, temp, (size_t)l * NH, bn, Kc, Vt, flag);
        attn_kernel<<<NB * NH * (SEQ / QT), 256, 0, stream>>>(bn, Kc, Vt, bn);
        if (big) {
            // proj split: kz0 -> h += (owner), kz1 -> Pp partial
            gemm_n64_dlds_kernel<<<dim3(DIM / 64, MTOK / 128, 2), 256, 0, stream>>>(
                bn, WcP, (size_t)l * DIM * DIM, nullptr, 0, h, Pp,
                MTOK, DIM, DIM, 8, flag);
        } else {
            gemm_mfma_n64_kernel<<<dim3(DIM / 64, MTOK / 128), 256, 0, stream>>>(
                bn, projw, (size_t)l * DIM * DIM, nullptr, 0, h,
                MTOK, DIM, DIM, 1, flag);
        }
        // ln2 folds Pp into h
        ln_kernel<<<MTOK / 4, 256, 0, stream>>>(h, big ? Pp : nullptr,
                                                ln2w, ln2b, (size_t)l * DIM, bn, flag);
        if (big) {
            gemm_n128_dlds_kernel<<<dim3(MLPD / 128, MTOK / 128), 256, 0, stream>>>(
                bn, WcW1, (size_t)l * MLPD * DIM, b1, (size_t)l * MLPD, Mb,
                MTOK, MLPD, DIM, 2 | 4, flag);
            // mlp2 split: kz0 -> h += (owner, +bias), kz1 -> Pm partial
            gemm_n64_dlds_kernel<<<dim3(DIM / 64, MTOK / 128, 2), 256, 0, stream>>>(
                Mb, WcW2, (size_t)l * DIM * MLPD, b2, (size_t)l * DIM, h, Pm,
                MTOK, DIM, MLPD, 8 | 4, flag);
        } else {
            gemm_mfma_kernel<<<dim3(MLPD / 128, MTOK / 128), 256, 0, stream>>>(
                bn, w1, (size_t)l * MLPD * DIM, b1, (size_t)l * MLPD, Mb,
                MTOK, MLPD, DIM, 2 | 4, flag);
            gemm_mfma_n64_kernel<<<dim3(DIM / 64, MTOK / 128), 256, 0, stream>>>(
                Mb, w2, (size_t)l * DIM * MLPD, b2, (size_t)l * DIM, h,
                MTOK, DIM, MLPD, 1 | 4, flag);
        }
    }

    // final LN folds the last layer's mlp2 partial
    lnf_kernel<<<MTOK, 256, 0, stream>>>(h, big ? Pm : nullptr, lnfw, lnfb, d_out, flag);
}

// Round 13
// 1009.328 us; speedup vs baseline: 1.0581x; 1.0581x over previous
//
#include <hip/hip_runtime.h>

// Problem constants
#define NB   4
#define SEQ  1024
#define DIM  512
#define NH   8
#define HD   64
#define MLPD 2048
#define NL   4
#define TOPKK 256
#define QKVD 1536   // 3*DIM
#define QT   16     // queries per attention block

typedef short bh8 __attribute__((ext_vector_type(8)));
typedef float f32x4 __attribute__((ext_vector_type(4)));

// ---------- helpers ----------
__device__ __forceinline__ float b2f(unsigned short v) {
    return __uint_as_float(((unsigned)v) << 16);
}
__device__ __forceinline__ unsigned short f2b(float f) {
    unsigned u = __float_as_uint(f);
    u += 0x7FFFu + ((u >> 16) & 1u);   // RNE
    return (unsigned short)(u >> 16);
}
__device__ __forceinline__ float ldin(const void* p, size_t i, int bf) {
    return bf ? b2f(((const unsigned short*)p)[i]) : ((const float*)p)[i];
}
__device__ __forceinline__ float wave_sum(float v) {
#pragma unroll
    for (int m = 32; m; m >>= 1) v += __shfl_xor(v, m);
    return v;
}
// monotone bf16-bits -> 16-bit radix key, and inverse
__device__ __forceinline__ unsigned f2key16(unsigned short u) {
    return (u & 0x8000u) ? (unsigned)((~u) & 0xFFFFu) : (unsigned)(u | 0x8000u);
}
__device__ __forceinline__ unsigned short key16b(unsigned k) {
    return (k & 0x8000u) ? (unsigned short)(k & 0x7FFFu)
                         : (unsigned short)((~k) & 0xFFFFu);
}
// packed 2xf32 -> 2xbf16 (HW RNE)
__device__ __forceinline__ unsigned cvtpk(float a, float b) {
    unsigned r;
    asm("v_cvt_pk_bf16_f32 %0, %1, %2" : "=v"(r) : "v"(a), "v"(b));
    return r;
}
// 8 contiguous fp32 -> packed bf16x8
__device__ __forceinline__ uint4 pack8(const float* __restrict__ p) {
    uint4 r;
    r.x = (unsigned)f2b(p[0]) | ((unsigned)f2b(p[1]) << 16);
    r.y = (unsigned)f2b(p[2]) | ((unsigned)f2b(p[3]) << 16);
    r.z = (unsigned)f2b(p[4]) | ((unsigned)f2b(p[5]) << 16);
    r.w = (unsigned)f2b(p[6]) | ((unsigned)f2b(p[7]) << 16);
    return r;
}
// async 16B/lane global->LDS: LDS dest = wave-uniform base + lane*16
__device__ __forceinline__ void async16(unsigned short* lds, const unsigned short* g) {
    __builtin_amdgcn_global_load_lds(
        (const __attribute__((address_space(1))) unsigned int*)g,
        (__attribute__((address_space(3))) unsigned int*)lds, 16, 0, 0);
}

// ---------- kernels ----------

__global__ void detect_kernel(const unsigned short* __restrict__ ln1w,
                              int* __restrict__ flag) {
    if (threadIdx.x == 0 && blockIdx.x == 0)
        *flag = (ln1w[0] == 0x3F80u) ? 1 : 0;
}

// convert weight array (input dtype) -> bf16 scratch
__global__ __launch_bounds__(256) void wcvt_kernel(
    const void* __restrict__ W, unsigned short* __restrict__ out,
    int n, const int* __restrict__ dflag) {
    int bf = *dflag;
    int idx = blockIdx.x * 256 + threadIdx.x;
    if (idx < n) out[idx] = f2b(ldin(W, idx, bf));
}

__global__ __launch_bounds__(256) void addpos_kernel(
    const void* __restrict__ x, const void* __restrict__ pos,
    float* __restrict__ h, const int* __restrict__ dflag) {
    int bf = *dflag;
    int idx = blockIdx.x * 256 + threadIdx.x;
    int sd = idx & (SEQ * DIM - 1);
    h[idx] = ldin(x, idx, bf) + ldin(pos, sd, bf);
}

// layernorm over last dim (512): fp32 in, bf16 out. w/b at element offset wo.
// one WAVE per row (4 rows/block), pure shfl reduce, no barriers/LDS.
__global__ __launch_bounds__(256) void ln_kernel(
    const float* __restrict__ in, const void* __restrict__ w,
    const void* __restrict__ bb, size_t wo, unsigned short* __restrict__ out,
    const int* __restrict__ dflag) {
    int bf = *dflag;
    int tid = threadIdx.x;
    int lane = tid & 63, wid = tid >> 6;
    int row = blockIdx.x * 4 + wid;
    const float* p = in + (size_t)row * DIM + lane * 8;
    float4 x0 = *(const float4*)(p);
    float4 x1 = *(const float4*)(p + 4);
    float d[8] = {x0.x, x0.y, x0.z, x0.w, x1.x, x1.y, x1.z, x1.w};
    float s = (d[0] + d[1]) + (d[2] + d[3]) + (d[4] + d[5]) + (d[6] + d[7]);
    s = wave_sum(s);
    float mean = s * (1.0f / DIM);
    float q = 0.f;
#pragma unroll
    for (int j = 0; j < 8; ++j) {
        d[j] -= mean;
        q += d[j] * d[j];
    }
    q = wave_sum(q);
    float rs = rsqrtf(q * (1.0f / DIM) + 1e-6f);
    size_t eo = wo + lane * 8;
    unsigned short* o = out + (size_t)row * DIM + lane * 8;
    unsigned pw[4];
#pragma unroll
    for (int j = 0; j < 4; ++j) {
        float v0 = d[2 * j]     * rs * ldin(w, eo + 2 * j, bf)     + ldin(bb, eo + 2 * j, bf);
        float v1 = d[2 * j + 1] * rs * ldin(w, eo + 2 * j + 1, bf) + ldin(bb, eo + 2 * j + 1, bf);
        pw[j] = (unsigned)f2b(v0) | ((unsigned)f2b(v1) << 16);
    }
    *(uint4*)o = (uint4){pw[0], pw[1], pw[2], pw[3]};
}

// final layernorm: fp32 in, output in detected dtype
__global__ __launch_bounds__(256) void lnf_kernel(
    const float* __restrict__ in, const void* __restrict__ w,
    const void* __restrict__ bb, void* __restrict__ out,
    const int* __restrict__ dflag) {
    int bf = *dflag;
    __shared__ float red[4];
    int row = blockIdx.x, tid = threadIdx.x;
    int lane = tid & 63, wid = tid >> 6;
    const float* p = in + (size_t)row * DIM;
    float x0 = p[tid], x1 = p[tid + 256];
    float s = wave_sum(x0 + x1);
    if (!lane) red[wid] = s;
    __syncthreads();
    float mean = (red[0] + red[1] + red[2] + red[3]) * (1.0f / DIM);
    float d0 = x0 - mean, d1 = x1 - mean;
    float q = wave_sum(d0 * d0 + d1 * d1);
    __syncthreads();
    if (!lane) red[wid] = q;
    __syncthreads();
    float var = (red[0] + red[1] + red[2] + red[3]) * (1.0f / DIM);
    float rs = rsqrtf(var + 1e-6f);
    float v0 = d0 * rs * ldin(w, tid, bf) + ldin(bb, tid, bf);
    float v1 = d1 * rs * ldin(w, tid + 256, bf) + ldin(bb, tid + 256, bf);
    size_t o = (size_t)row * DIM;
    if (bf) {
        ((unsigned short*)out)[o + tid]       = f2b(v0);
        ((unsigned short*)out)[o + tid + 256] = f2b(v1);
    } else {
        ((float*)out)[o + tid]       = v0;
        ((float*)out)[o + tid + 256] = v1;
    }
}

// ---- fallback GEMMs (inline fp32->bf16 pack) ----
__global__ __launch_bounds__(256) void gemm_mfma_kernel(
    const unsigned short* __restrict__ A, const void* __restrict__ W, size_t wo,
    const void* __restrict__ bias, size_t bo, void* __restrict__ C,
    int M, int N, int K, int flags, const int* __restrict__ dflag) {
    int bf = *dflag;
    __shared__ unsigned short As[128 * 32];
    __shared__ unsigned short Bs[128 * 32];
    int tid = threadIdx.x;
    int w = tid >> 6, l = tid & 63;
    int n0 = blockIdx.x * 128, m0 = blockIdx.y * 128;
    int wm = (w >> 1) * 64, wn = (w & 1) * 64;
    int lq = l & 15, lk = l >> 4;

    int srow = w * 32 + (l >> 2);
    int cb = (l & 3) * 8;
    const unsigned short* aG = A + (size_t)(m0 + srow) * K + cb;
    size_t wb = wo + (size_t)(n0 + srow) * K + cb;
    unsigned short* sA0 = &As[w * 1024 + l * 8];
    unsigned short* sA1 = &As[w * 1024 + 512 + l * 8];
    unsigned short* sB0 = &Bs[w * 1024 + l * 8];
    unsigned short* sB1 = &Bs[w * 1024 + 512 + l * 8];

    f32x4 acc[4][4];
#pragma unroll
    for (int i = 0; i < 4; ++i)
#pragma unroll
        for (int j = 0; j < 4; ++j)
            acc[i][j] = (f32x4){0.f, 0.f, 0.f, 0.f};

    for (int k0 = 0; k0 < K; k0 += 32) {
        uint4 a0 = *(const uint4*)(aG + k0);
        uint4 a1 = *(const uint4*)(aG + 16 * K + k0);
        uint4 b0, b1;
        if (bf) {
            b0 = *(const uint4*)((const unsigned short*)W + wb + k0);
            b1 = *(const uint4*)((const unsigned short*)W + wb + 16 * K + k0);
        } else {
            b0 = pack8((const float*)W + wb + k0);
            b1 = pack8((const float*)W + wb + 16 * K + k0);
        }
        __syncthreads();
        *(uint4*)sA0 = a0;
        *(uint4*)sA1 = a1;
        *(uint4*)sB0 = b0;
        *(uint4*)sB1 = b1;
        __syncthreads();
        bh8 af[4], bw[4];
#pragma unroll
        for (int i = 0; i < 4; ++i) {
            af[i] = *(const bh8*)&As[(wm + i * 16 + lq) * 32 + lk * 8];
            bw[i] = *(const bh8*)&Bs[(wn + i * 16 + lq) * 32 + lk * 8];
        }
#pragma unroll
        for (int i = 0; i < 4; ++i)
#pragma unroll
            for (int j = 0; j < 4; ++j)
                acc[i][j] = __builtin_amdgcn_mfma_f32_16x16x32_bf16(
                    af[i], bw[j], acc[i][j], 0, 0, 0);
    }

    int lr4 = lk * 4;
#pragma unroll
    for (int i = 0; i < 4; ++i) {
#pragma unroll
        for (int j = 0; j < 4; ++j) {
            int n = n0 + wn + j * 16 + lq;
            float bv = (flags & 4) ? ldin(bias, bo + n, bf) : 0.0f;
#pragma unroll
            for (int r = 0; r < 4; ++r) {
                int m = m0 + wm + i * 16 + lr4 + r;
                float v = acc[i][j][r] + bv;
                if (flags & 2) v = 0.5f * v * (1.0f + erff(v * 0.70710678118654752f));
                size_t o = (size_t)m * N + n;
                if (flags & 1) ((float*)C)[o] += v;
                else           ((unsigned short*)C)[o] = f2b(v);
            }
        }
    }
}

__global__ __launch_bounds__(256) void gemm_mfma_n64_kernel(
    const unsigned short* __restrict__ A, const void* __restrict__ W, size_t wo,
    const void* __restrict__ bias, size_t bo, void* __restrict__ C,
    int M, int N, int K, int flags, const int* __restrict__ dflag) {
    int bf = *dflag;
    __shared__ unsigned short As[128 * 32];
    __shared__ unsigned short Bs[64 * 32];
    int tid = threadIdx.x;
    int w = tid >> 6, l = tid & 63;
    int n0 = blockIdx.x * 64, m0 = blockIdx.y * 128;
    int wm = (w >> 1) * 64, wn = (w & 1) * 32;
    int lq = l & 15, lk = l >> 4;

    int srowA = w * 32 + (l >> 2);
    int cb = (l & 3) * 8;
    const unsigned short* aG = A + (size_t)(m0 + srowA) * K + cb;
    int srowB = w * 16 + (l >> 2);
    size_t wb = wo + (size_t)(n0 + srowB) * K + cb;
    unsigned short* sA0 = &As[w * 1024 + l * 8];
    unsigned short* sA1 = &As[w * 1024 + 512 + l * 8];
    unsigned short* sB0 = &Bs[w * 512 + l * 8];

    f32x4 acc[4][2];
#pragma unroll
    for (int i = 0; i < 4; ++i) {
        acc[i][0] = (f32x4){0.f, 0.f, 0.f, 0.f};
        acc[i][1] = (f32x4){0.f, 0.f, 0.f, 0.f};
    }

    for (int k0 = 0; k0 < K; k0 += 32) {
        uint4 a0 = *(const uint4*)(aG + k0);
        uint4 a1 = *(const uint4*)(aG + 16 * K + k0);
        uint4 b0;
        if (bf) b0 = *(const uint4*)((const unsigned short*)W + wb + k0);
        else    b0 = pack8((const float*)W + wb + k0);
        __syncthreads();
        *(uint4*)sA0 = a0;
        *(uint4*)sA1 = a1;
        *(uint4*)sB0 = b0;
        __syncthreads();
        bh8 af[4], bw[2];
#pragma unroll
        for (int i = 0; i < 4; ++i)
            af[i] = *(const bh8*)&As[(wm + i * 16 + lq) * 32 + lk * 8];
        bw[0] = *(const bh8*)&Bs[(wn + lq) * 32 + lk * 8];
        bw[1] = *(const bh8*)&Bs[(wn + 16 + lq) * 32 + lk * 8];
#pragma unroll
        for (int i = 0; i < 4; ++i) {
            acc[i][0] = __builtin_amdgcn_mfma_f32_16x16x32_bf16(af[i], bw[0], acc[i][0], 0, 0, 0);
            acc[i][1] = __builtin_amdgcn_mfma_f32_16x16x32_bf16(af[i], bw[1], acc[i][1], 0, 0, 0);
        }
    }

    int lr4 = lk * 4;
#pragma unroll
    for (int i = 0; i < 4; ++i) {
#pragma unroll
        for (int j = 0; j < 2; ++j) {
            int n = n0 + wn + j * 16 + lq;
            float bv = (flags & 4) ? ldin(bias, bo + n, bf) : 0.0f;
#pragma unroll
            for (int r = 0; r < 4; ++r) {
                int m = m0 + wm + i * 16 + lr4 + r;
                float v = acc[i][j][r] + bv;
                if (flags & 2) v = 0.5f * v * (1.0f + erff(v * 0.70710678118654752f));
                size_t o = (size_t)m * N + n;
                if (flags & 1) ((float*)C)[o] += v;
                else           ((unsigned short*)C)[o] = f2b(v);
            }
        }
    }
}

// ---- main-path GEMM: 128Mx64N, bf16 weights, global_load_lds staging.
// Double-buffered 2-phase pipeline with raw barriers + counted drain:
//   prologue stage buf0; per iter: vmcnt(0) [prev loads] -> s_barrier ->
//   issue next tile into buf^1 -> ds_read+MFMA on buf.
// Accumulation order unchanged -> bitwise-identical results.
// flags: 1 = plain fp32 +=, 2 = GELU->bf16, 0 = bf16 store, 4 = bias, 8 = atomic +=
__global__ __launch_bounds__(256) void gemm_n64_dlds_kernel(
    const unsigned short* __restrict__ A, const unsigned short* __restrict__ W, size_t wo,
    const void* __restrict__ bias, size_t bo, void* __restrict__ C,
    int M, int N, int K, int flags, const int* __restrict__ dflag) {
    __shared__ unsigned short As[2][128 * 32];
    __shared__ unsigned short Bs[2][64 * 32];
    int tid = threadIdx.x;
    int w = tid >> 6, l = tid & 63;
    int n0 = blockIdx.x * 64, m0 = blockIdx.y * 128;
    int kz = blockIdx.z;
    int Ks = K / (int)gridDim.z;
    int kbeg = kz * Ks;
    int nt = Ks / 32;
    int wm = (w >> 1) * 64, wn = (w & 1) * 32;
    int lq = l & 15, lk = l >> 4;

    int srowA = w * 32 + (l >> 2);
    int srowB = w * 16 + (l >> 2);
    int cb = (l & 3) * 8;
    const unsigned short* aG = A + (size_t)(m0 + srowA) * K + cb + kbeg;
    const unsigned short* wG = W + wo + (size_t)(n0 + srowB) * K + cb + kbeg;

    f32x4 acc[4][2];
#pragma unroll
    for (int i = 0; i < 4; ++i) {
        acc[i][0] = (f32x4){0.f, 0.f, 0.f, 0.f};
        acc[i][1] = (f32x4){0.f, 0.f, 0.f, 0.f};
    }

    // prologue: stage tile 0 into buffer 0
    async16(&As[0][w * 1024], aG);
    async16(&As[0][w * 1024 + 512], aG + 16 * K);
    async16(&Bs[0][w * 512], wG);

    int cur = 0;
    for (int t = 0; t < nt; ++t) {
        // wait this wave's buf[cur] loads; raw barrier = all waves' loads
        // landed AND all waves' prior-iter ds_reads (into regs) done.
        asm volatile("s_waitcnt vmcnt(0)" ::: "memory");
        __builtin_amdgcn_s_barrier();
        if (t + 1 < nt) {
            int k1 = (t + 1) * 32;
            async16(&As[cur ^ 1][w * 1024], aG + k1);
            async16(&As[cur ^ 1][w * 1024 + 512], aG + 16 * K + k1);
            async16(&Bs[cur ^ 1][w * 512], wG + k1);
        }
        bh8 af[4], bw[2];
#pragma unroll
        for (int i = 0; i < 4; ++i)
            af[i] = *(const bh8*)&As[cur][(wm + i * 16 + lq) * 32 + lk * 8];
        bw[0] = *(const bh8*)&Bs[cur][(wn + lq) * 32 + lk * 8];
        bw[1] = *(const bh8*)&Bs[cur][(wn + 16 + lq) * 32 + lk * 8];
#pragma unroll
        for (int i = 0; i < 4; ++i) {
            acc[i][0] = __builtin_amdgcn_mfma_f32_16x16x32_bf16(af[i], bw[0], acc[i][0], 0, 0, 0);
            acc[i][1] = __builtin_amdgcn_mfma_f32_16x16x32_bf16(af[i], bw[1], acc[i][1], 0, 0, 0);
        }
        cur ^= 1;
    }

    int bf = (flags & 4) ? *dflag : 0;
    int lr4 = lk * 4;
#pragma unroll
    for (int i = 0; i < 4; ++i) {
#pragma unroll
        for (int j = 0; j < 2; ++j) {
            int n = n0 + wn + j * 16 + lq;
            float bv = ((flags & 4) && kz == 0) ? ldin(bias, bo + n, bf) : 0.0f;
#pragma unroll
            for (int r = 0; r < 4; ++r) {
                int m = m0 + wm + i * 16 + lr4 + r;
                float v = acc[i][j][r] + bv;
                if (flags & 2) v = 0.5f * v * (1.0f + erff(v * 0.70710678118654752f));
                size_t o = (size_t)m * N + n;
                if (flags & 8)      atomicAdd(&((float*)C)[o], v);
                else if (flags & 1) ((float*)C)[o] += v;
                else                ((unsigned short*)C)[o] = f2b(v);
            }
        }
    }
}

// fused depthwise conv (k=3 along s) + q/k normalize + scatter.
__global__ __launch_bounds__(256) void dwqkv_kernel(
    const unsigned short* __restrict__ in, const void* __restrict__ w, size_t wo,
    const void* __restrict__ temp, size_t to,
    unsigned short* __restrict__ qn, unsigned short* __restrict__ Kc,
    unsigned short* __restrict__ Vt, const int* __restrict__ dflag) {
    int bf = *dflag;
    int tid = threadIdx.x;
    int g = tid >> 6, c = tid & 63;
    int gid = blockIdx.x * 4 + g;          // (b*S+s)*H + h
    int h = gid & 7;
    int bs = gid >> 3;
    int s = bs & (SEQ - 1), b = bs >> 10;
    int bh = b * NH + h;
    const unsigned short* row = in + (size_t)bs * QKVD;
    float vals[3];
#pragma unroll
    for (int t = 0; t < 3; ++t) {
        int o = t * 512 + h * HD + c;
        float w0 = ldin(w, wo + o * 3 + 0, bf);
        float w1 = ldin(w, wo + o * 3 + 1, bf);
        float w2 = ldin(w, wo + o * 3 + 2, bf);
        float a = w1 * b2f(row[o]);
        if (s > 0)       a += w0 * b2f(row[o - QKVD]);
        if (s < SEQ - 1) a += w2 * b2f(row[o + QKVD]);
        vals[t] = a;
    }
    float qs = wave_sum(vals[0] * vals[0]);
    float ks = wave_sum(vals[1] * vals[1]);
    float t_ = ldin(temp, to + h, bf);
    qn[(size_t)bs * DIM + h * HD + c] = f2b(vals[0] / fmaxf(sqrtf(qs), 1e-12f) * t_);
    Kc[((size_t)bh * SEQ + s) * HD + c] = f2b(vals[1] / fmaxf(sqrtf(ks), 1e-12f));
    Vt[(((size_t)bh * 32 + (s >> 5)) * HD + c) * 32 + (s & 31)] = f2b(vals[2]);
}

// Q-tiled MFMA attention (v5 structure + dual-row select ILP).
// select phase processes TWO rows per iteration — independent serial chains
// (16-step ballot search, shfl reductions) interleave as ILP.
__global__ __launch_bounds__(256) void attn_kernel(
    const unsigned short* __restrict__ q, const unsigned short* __restrict__ Kc,
    const unsigned short* __restrict__ Vt, unsigned short* __restrict__ outp) {
    __shared__ __align__(16) unsigned short sc16[QT * 1024];

    int tid = threadIdx.x;
    int w = tid >> 6, l = tid & 63;
    int lq = l & 15, lk = l >> 4;
    int bid = blockIdx.x;
    int qt = (bid >> 3) & 63;
    int bh = ((bid >> 9) << 3) | (bid & 7);   // XCD-locality remap (bijective)
    int h = bh & 7;
    int b = bh >> 3;

    // q rows have stride DIM (written by dwqkv into a dense (B*S, D) buffer)
    const unsigned short* qp = q + (size_t)(b * SEQ + qt * QT + lq) * DIM + h * HD + lk * 8;
    bh8 aq0 = *(const bh8*)(qp);
    bh8 aq1 = *(const bh8*)(qp + 32);

    int swz = ((lq ^ (lq >> 2)) & 7) << 1;   // per-q-row chunk4 XOR (bits 1-3)

    // QK^T: wave w computes keys [w*256,(w+1)*256) for all 16 queries.
    // mfma(K,Q): lane (lq,lk) -> q-row lq, keys key0 + lk*4 .. +3.
    const unsigned short* Kbh = Kc + (size_t)bh * SEQ * HD;
    unsigned short* srowq = sc16 + lq * 1024;
    for (int kb = 0; kb < 16; kb += 2) {
        int key0 = (w * 16 + kb) * 16;
        const unsigned short* kp0 = Kbh + (size_t)(key0 + lq) * HD + lk * 8;
        const unsigned short* kp1 = kp0 + 16 * HD;
        bh8 b0 = *(const bh8*)(kp0);
        bh8 b1 = *(const bh8*)(kp0 + 32);
        bh8 b2 = *(const bh8*)(kp1);
        bh8 b3 = *(const bh8*)(kp1 + 32);
        f32x4 a0 = {0.f, 0.f, 0.f, 0.f};
        f32x4 a1 = {0.f, 0.f, 0.f, 0.f};
        a0 = __builtin_amdgcn_mfma_f32_16x16x32_bf16(b0, aq0, a0, 0, 0, 0);
        a0 = __builtin_amdgcn_mfma_f32_16x16x32_bf16(b1, aq1, a0, 0, 0, 0);
        a1 = __builtin_amdgcn_mfma_f32_16x16x32_bf16(b2, aq0, a1, 0, 0, 0);
        a1 = __builtin_amdgcn_mfma_f32_16x16x32_bf16(b3, aq1, a1, 0, 0, 0);
        int c0 = (key0 >> 2) + lk;           // chunk4 index of first 4 keys
        uint2 w0 = {cvtpk(a0[0], a0[1]), cvtpk(a0[2], a0[3])};
        uint2 w1 = {cvtpk(a1[0], a1[1]), cvtpk(a1[2], a1[3])};
        *(uint2*)&srowq[(c0 ^ swz) << 2]       = w0;
        *(uint2*)&srowq[((c0 + 4) ^ swz) << 2] = w1;
    }
    __syncthreads();

    // fused top-k select + softmax: wave w owns rows w*4..w*4+3,
    // processed two-at-a-time for chain-level ILP.
    for (int rr = 0; rr < 4; rr += 2) {
        int rowA = w * 4 + rr;
        unsigned short* sAr = sc16 + rowA * 1024;
        unsigned short* sBr = sc16 + (rowA + 1) * 1024;
        uint4 ra0 = *(const uint4*)&sAr[l * 8];
        uint4 ra1 = *(const uint4*)&sAr[512 + l * 8];
        uint4 rb0 = *(const uint4*)&sBr[l * 8];
        uint4 rb1 = *(const uint4*)&sBr[512 + l * 8];
        unsigned wa[8] = {ra0.x, ra0.y, ra0.z, ra0.w, ra1.x, ra1.y, ra1.z, ra1.w};
        unsigned wb[8] = {rb0.x, rb0.y, rb0.z, rb0.w, rb1.x, rb1.y, rb1.z, rb1.w};
        float va[16], vb[16];
#pragma unroll
        for (int j = 0; j < 8; ++j) {
            va[2 * j]     = __uint_as_float(wa[j] << 16);
            va[2 * j + 1] = __uint_as_float(wa[j] & 0xFFFF0000u);
            vb[2 * j]     = __uint_as_float(wb[j] << 16);
            vb[2 * j + 1] = __uint_as_float(wb[j] & 0xFFFF0000u);
        }
        // row maxes (independent chains)
        float ma = va[0], mb = vb[0];
#pragma unroll
        for (int j = 1; j < 16; ++j) {
            ma = fmaxf(ma, va[j]);
            mb = fmaxf(mb, vb[j]);
        }
#pragma unroll
        for (int off = 1; off < 64; off <<= 1) {
            ma = fmaxf(ma, __shfl_xor(ma, off));
            mb = fmaxf(mb, __shfl_xor(mb, off));
        }
        ma = fminf(fmaxf(ma, -10000.f), 10000.f);
        mb = fminf(fmaxf(mb, -10000.f), 10000.f);
        // dual ballot binary search (independent step chains)
        unsigned Ta = 0, Tb = 0;
        for (int bit = 15; bit >= 0; --bit) {
            unsigned ca = Ta | (1u << bit), cb = Tb | (1u << bit);
            float tfa = b2f(key16b(ca)), tfb = b2f(key16b(cb));
            unsigned cna = 0, cnb = 0;
#pragma unroll
            for (int j = 0; j < 16; ++j) {
                cna += (unsigned)__popcll(__ballot(va[j] >= tfa));
                cnb += (unsigned)__popcll(__ballot(vb[j] >= tfb));
            }
            if (cna >= TOPKK) Ta = ca;
            if (cnb >= TOPKK) Tb = cb;
        }
        float ka = b2f(key16b(Ta)), kb = b2f(key16b(Tb));
        // exp + sum (excluded -> exactly 0.0f)
        float sa = 0.f, sb = 0.f;
#pragma unroll
        for (int j = 0; j < 16; ++j) {
            float aa = fminf(fmaxf(va[j], -10000.f), 10000.f);
            float ab = fminf(fmaxf(vb[j], -10000.f), 10000.f);
            float ea = (va[j] >= ka) ? __expf(aa - ma) : 0.0f;
            float eb = (vb[j] >= kb) ? __expf(ab - mb) : 0.0f;
            sa += ea; sb += eb;
            va[j] = ea; vb[j] = eb;
        }
#pragma unroll
        for (int off = 1; off < 64; off <<= 1) {
            sa += __shfl_xor(sa, off);
            sb += __shfl_xor(sb, off);
        }
        float ia = 1.0f / sa, ib = 1.0f / sb;
        // pre-scale by 1/sum, pack to bf16 (HW RNE), write back in place
        unsigned pa[8], pb[8];
#pragma unroll
        for (int j = 0; j < 8; ++j) {
            pa[j] = cvtpk(va[2 * j] * ia, va[2 * j + 1] * ia);
            pb[j] = cvtpk(vb[2 * j] * ib, vb[2 * j + 1] * ib);
        }
        *(uint4*)&sAr[l * 8]       = (uint4){pa[0], pa[1], pa[2], pa[3]};
        *(uint4*)&sAr[512 + l * 8] = (uint4){pa[4], pa[5], pa[6], pa[7]};
        *(uint4*)&sBr[l * 8]       = (uint4){pb[0], pb[1], pb[2], pb[3]};
        *(uint4*)&sBr[512 + l * 8] = (uint4){pb[4], pb[5], pb[6], pb[7]};
    }
    __syncthreads();

    // PV (P already normalized); P fragment read applies the same chunk4 XOR
    {
        const unsigned short* Vbh = Vt + (size_t)bh * SEQ * HD;
        const unsigned short* prow = sc16 + lq * 1024;
        f32x4 oacc = {0.f, 0.f, 0.f, 0.f};
        for (int tc = 0; tc < 32; tc += 2) {
            const unsigned short* vp0 = Vbh + (size_t)tc * 2048 + (w * 16 + lq) * 32 + lk * 8;
            bh8 bv0 = *(const bh8*)(vp0);
            bh8 bv1 = *(const bh8*)(vp0 + 2048);
            bh8 ap0 = *(const bh8*)&prow[((tc * 8 + lk * 2) ^ swz) << 2];
            bh8 ap1 = *(const bh8*)&prow[(((tc + 1) * 8 + lk * 2) ^ swz) << 2];
            oacc = __builtin_amdgcn_mfma_f32_16x16x32_bf16(ap0, bv0, oacc, 0, 0, 0);
            oacc = __builtin_amdgcn_mfma_f32_16x16x32_bf16(ap1, bv1, oacc, 0, 0, 0);
        }
#pragma unroll
        for (int r = 0; r < 4; ++r) {
            int qrow = lk * 4 + r;
            outp[((size_t)(b * SEQ + qt * QT + qrow)) * DIM + h * HD + w * 16 + lq] = f2b(oacc[r]);
        }
    }
}

// ---------- host ----------
extern "C" void kernel_launch(void* const* d_in, const int* in_sizes, int n_in,
                              void* d_out, int out_size, void* d_ws, size_t ws_size,
                              hipStream_t stream) {
    (void)in_sizes; (void)n_in; (void)out_size;
    const void* x     = d_in[0];
    const void* pos   = d_in[1];
    const void* ln1w  = d_in[2];
    const void* ln1b  = d_in[3];
    const void* qkvw  = d_in[4];
    const void* dww   = d_in[5];
    const void* temp  = d_in[6];
    const void* projw = d_in[7];
    const void* ln2w  = d_in[8];
    const void* ln2b  = d_in[9];
    const void* w1    = d_in[10];
    const void* b1    = d_in[11];
    const void* w2    = d_in[12];
    const void* b2    = d_in[13];
    const void* lnfw  = d_in[14];
    const void* lnfb  = d_in[15];

    // ws layout (float units): h[0,2M) | bn@2M (ln out / q / attn out) |
    // C2@3M (qkv pre-conv / MLP mid) | Vt@6M | Kc@7M | flag@9M | Wc@(9M+16)
    float* wsf = (float*)d_ws;
    const size_t M1 = (size_t)1024 * 1024;
    float*          h    = wsf;
    unsigned short* bn   = (unsigned short*)(wsf + 2 * M1);
    unsigned short* C2   = (unsigned short*)(wsf + 3 * M1);
    unsigned short* Vt   = (unsigned short*)(wsf + 6 * M1);
    unsigned short* Kc   = (unsigned short*)(wsf + 7 * M1);
    unsigned short* Mb   = C2;
    int*            flag = (int*)(wsf + 9 * M1);
    unsigned short* Wc   = (unsigned short*)(wsf + 9 * M1 + 16);

    const int MTOK  = NB * SEQ;                       // 4096
    const int nQKVW = NL * QKVD * DIM;                // 3145728
    const int nPROJ = NL * DIM * DIM;                 // 1048576
    const int nW1   = NL * MLPD * DIM;                // 4194304
    const int nW2   = NL * DIM * MLPD;                // 4194304
    const size_t wcElems = (size_t)nQKVW + nPROJ + nW1 + nW2;   // 12582912
    const int big = ws_size >= ((9 * M1 + 16) * 4 + wcElems * 2);

    unsigned short* WcQ  = Wc;
    unsigned short* WcP  = Wc + nQKVW;
    unsigned short* WcW1 = Wc + nQKVW + nPROJ;
    unsigned short* WcW2 = Wc + nQKVW + nPROJ + (size_t)nW1;

    detect_kernel<<<1, 64, 0, stream>>>((const unsigned short*)ln1w, flag);
    addpos_kernel<<<(NB * SEQ * DIM) / 256, 256, 0, stream>>>(x, pos, h, flag);

    if (big) {
        wcvt_kernel<<<nQKVW / 256, 256, 0, stream>>>(qkvw, WcQ, nQKVW, flag);
        wcvt_kernel<<<nPROJ / 256, 256, 0, stream>>>(projw, WcP, nPROJ, flag);
        wcvt_kernel<<<nW1 / 256, 256, 0, stream>>>(w1, WcW1, nW1, flag);
        wcvt_kernel<<<nW2 / 256, 256, 0, stream>>>(w2, WcW2, nW2, flag);
    }

    for (int l = 0; l < NL; ++l) {
        ln_kernel<<<MTOK / 4, 256, 0, stream>>>(h, ln1w, ln1b, (size_t)l * DIM, bn, flag);
        if (big) {
            gemm_n64_dlds_kernel<<<dim3(QKVD / 64, MTOK / 128, 1), 256, 0, stream>>>(
                bn, WcQ, (size_t)l * QKVD * DIM, nullptr, 0, C2,
                MTOK, QKVD, DIM, 0, flag);
        } else {
            gemm_mfma_kernel<<<dim3(QKVD / 128, MTOK / 128), 256, 0, stream>>>(
                bn, qkvw, (size_t)l * QKVD * DIM, nullptr, 0, C2,
                MTOK, QKVD, DIM, 0, flag);
        }
        // fused conv+prep: reads C2, writes q->bn, Kc, Vt (no alias)
        dwqkv_kernel<<<(NB * SEQ * NH) / 4, 256, 0, stream>>>(
            C2, dww, (size_t)l * QKVD * 3, temp, (size_t)l * NH, bn, Kc, Vt, flag);
        // attn: q from bn (stride DIM), output in-place to bn (disjoint regions)
        attn_kernel<<<NB * NH * (SEQ / QT), 256, 0, stream>>>(bn, Kc, Vt, bn);
        if (big) {
            gemm_n64_dlds_kernel<<<dim3(DIM / 64, MTOK / 128, 2), 256, 0, stream>>>(
                bn, WcP, (size_t)l * DIM * DIM, nullptr, 0, h,
                MTOK, DIM, DIM, 8, flag);
        } else {
            gemm_mfma_n64_kernel<<<dim3(DIM / 64, MTOK / 128), 256, 0, stream>>>(
                bn, projw, (size_t)l * DIM * DIM, nullptr, 0, h,
                MTOK, DIM, DIM, 1, flag);
        }
        ln_kernel<<<MTOK / 4, 256, 0, stream>>>(h, ln2w, ln2b, (size_t)l * DIM, bn, flag);
        if (big) {
            gemm_n64_dlds_kernel<<<dim3(MLPD / 64, MTOK / 128, 1), 256, 0, stream>>>(
                bn, WcW1, (size_t)l * MLPD * DIM, b1, (size_t)l * MLPD, Mb,
                MTOK, MLPD, DIM, 2 | 4, flag);
            gemm_n64_dlds_kernel<<<dim3(DIM / 64, MTOK / 128, 2), 256, 0, stream>>>(
                Mb, WcW2, (size_t)l * DIM * MLPD, b2, (size_t)l * DIM, h,
                MTOK, DIM, MLPD, 8 | 4, flag);
        } else {
            gemm_mfma_kernel<<<dim3(MLPD / 128, MTOK / 128), 256, 0, stream>>>(
                bn, w1, (size_t)l * MLPD * DIM, b1, (size_t)l * MLPD, Mb,
                MTOK, MLPD, DIM, 2 | 4, flag);
            gemm_mfma_n64_kernel<<<dim3(DIM / 64, MTOK / 128), 256, 0, stream>>>(
                Mb, w2, (size_t)l * DIM * MLPD, b2, (size_t)l * DIM, h,
                MTOK, DIM, MLPD, 1 | 4, flag);
        }
    }

    lnf_kernel<<<MTOK, 256, 0, stream>>>(h, lnfw, lnfb, d_out, flag);
}